// Round 1
// baseline (9728.228 us; speedup 1.0000x reference)
//
#include <hip/hip_runtime.h>

// PyramidSampler: B=4 clouds of P=8192 pts, D=512 feats, scales (1.0, 0.5, 0.25).
// Scale 0.25's FPS indices are an exact prefix of scale 0.5's (scan step is
// length-independent), so we run FPS once per batch for 4096 steps.

constexpr int kB  = 4;
constexpr int kP  = 8192;
constexpr int kD  = 512;
constexpr int kN1 = 4096;               // int(P*0.5)
constexpr int kN2 = 2048;               // int(P*0.25)
constexpr int kS  = kP + kN1 + kN2;     // 14336 rows per batch in fused output
constexpr int kFpsThreads = 1024;       // 16 waves, one block per batch (1 CU)
constexpr int kPPT = 8;                 // points per thread: 8192/1024

// ---------------------------------------------------------------------------
// FPS kernel: one block per batch. Points live in registers (blocked layout:
// thread t owns points [t*8, t*8+8)). Per step:
//   - update dist[k] = min(dist[k], |p_k - c|^2)  (exact mul/add, no fma,
//     left-fold (dx^2+dy^2)+dz^2 to match XLA)
//   - block argmax via packed u64 key = (dist_bits<<32) | (8191 - idx);
//     max-key picks max dist, ties -> smallest original index (matches
//     jnp.argmax first-occurrence semantics)
//   - owner thread broadcasts new centroid through LDS
// ---------------------------------------------------------------------------
__global__ __launch_bounds__(kFpsThreads)
void fps_kernel(const float* __restrict__ pos, int* __restrict__ idx_out) {
  const int b   = blockIdx.x;
  const int tid = threadIdx.x;
  const float* pb = pos + (size_t)b * kP * 3;
  int* idx = idx_out + b * kN1;

  __shared__ unsigned long long lds_key[kFpsThreads / 64];
  __shared__ float lds_c[3];

  float px[kPPT], py[kPPT], pz[kPPT], dist[kPPT];
  {
    // thread t reads floats [t*24, t*24+24): 6 coalesced float4 loads
    float f[24];
    const float4* pb4 = reinterpret_cast<const float4*>(pb) + tid * 6;
#pragma unroll
    for (int i = 0; i < 6; ++i) {
      float4 v = pb4[i];
      f[4*i+0] = v.x; f[4*i+1] = v.y; f[4*i+2] = v.z; f[4*i+3] = v.w;
    }
#pragma unroll
    for (int k = 0; k < kPPT; ++k) {
      px[k] = f[3*k+0];
      py[k] = f[3*k+1];
      pz[k] = f[3*k+2];
      dist[k] = 1e10f;                       // BIG
    }
  }
  if (tid == 0) { lds_c[0] = px[0]; lds_c[1] = py[0]; lds_c[2] = pz[0]; }
  __syncthreads();

  int far = 0;
  const int lo_base = (kP - 1) - tid * kPPT;  // lo = 8191 - global_idx

  for (int s = 0; ; ++s) {
    if (tid == 0) idx[s] = far;              // scan outputs far BEFORE update
    if (s == kN1 - 1) break;                 // last index written; no update

    const float cx = lds_c[0], cy = lds_c[1], cz = lds_c[2];

    float vbest = -1.0f;
    int lobest = 0;
    {
#pragma clang fp contract(off)
#pragma unroll
      for (int k = 0; k < kPPT; ++k) {
        float dx = px[k] - cx;
        float dy = py[k] - cy;
        float dz = pz[k] - cz;
        float d  = dx * dx + dy * dy;        // exact: mul,mul,add
        d = d + dz * dz;                     // then add (XLA left-fold)
        float dk = fminf(dist[k], d);
        dist[k] = dk;
        bool gt = dk > vbest;                // strict: first-k wins ties
        vbest  = gt ? dk : vbest;
        lobest = gt ? (lo_base - k) : lobest;
      }
    }
    // dist >= 0 so float bits are order-preserving as u32
    unsigned long long key =
        ((unsigned long long)__float_as_uint(vbest) << 32) | (unsigned)lobest;
#pragma unroll
    for (int m = 32; m >= 1; m >>= 1) {
      unsigned long long o = __shfl_xor(key, m, 64);
      if (o > key) key = o;
    }
    if ((tid & 63) == 0) lds_key[tid >> 6] = key;
    __syncthreads();

    unsigned long long bb = lds_key[0];
#pragma unroll
    for (int w = 1; w < kFpsThreads / 64; ++w) {
      unsigned long long o = lds_key[w];
      if (o > bb) bb = o;
    }
    const int nf = (kP - 1) - (int)(unsigned)(bb & 0xFFFFFFFFull);

    // owner broadcasts the new centroid (static-index select, no scratch)
    const int kk = nf - tid * kPPT;
    if (0 <= kk && kk < kPPT) {
      float sx = px[0], sy = py[0], sz = pz[0];
#pragma unroll
      for (int k = 1; k < kPPT; ++k) {
        if (k == kk) { sx = px[k]; sy = py[k]; sz = pz[k]; }
      }
      lds_c[0] = sx; lds_c[1] = sy; lds_c[2] = sz;
    }
    far = nf;
    __syncthreads();
  }
}

// ---------------------------------------------------------------------------
// Gather/assemble kernel. Output layout:
//   fused_x: [B][14336][512]  (rows: 0..8191 identity, 8192..12287 idx[0..4095],
//                              12288..14335 idx[0..2047] (prefix))
//   fused_p: [B][14336][3]    appended after fused_x
// 256 threads/block; x-blocks copy 2 rows (128 float4 lanes each);
// pos-blocks copy 256 scalar floats.
// ---------------------------------------------------------------------------
constexpr int kXRows     = kB * kS;                    // 57344
constexpr int kXBlocks   = kXRows / 2;                 // 28672
constexpr int kPosElems  = kB * kS * 3;                // 172032
constexpr int kPosBlocks = kPosElems / 256;            // 672

__device__ __forceinline__ int src_row(int b, int r, const int* __restrict__ idx) {
  int s;
  if (r < kP)            s = r;
  else if (r < kP + kN1) s = idx[b * kN1 + (r - kP)];
  else                   s = idx[b * kN1 + (r - kP - kN1)];
  return b * kP + s;
}

__global__ __launch_bounds__(256)
void gather_kernel(const float* __restrict__ x, const float* __restrict__ pos,
                   const int* __restrict__ idx, float* __restrict__ out) {
  const int blk = blockIdx.x;
  if (blk < kXBlocks) {
    const int row  = blk * 2 + (threadIdx.x >> 7);    // 2 rows per block
    const int lane = threadIdx.x & 127;               // 128 float4 per row
    const int b = row / kS;
    const int r = row - b * kS;
    const int sr = src_row(b, r, idx);
    const float4* src4 = reinterpret_cast<const float4*>(x + (size_t)sr * kD);
    float4* dst4       = reinterpret_cast<float4*>(out + (size_t)row * kD);
    dst4[lane] = src4[lane];
  } else {
    const int e = (blk - kXBlocks) * 256 + threadIdx.x;   // [0, kPosElems)
    const int row = e / 3;
    const int c   = e - row * 3;
    const int b = row / kS;
    const int r = row - b * kS;
    const int sr = src_row(b, r, idx);
    float* outp = out + (size_t)kB * kS * kD;
    outp[e] = pos[sr * 3 + c];
  }
}

extern "C" void kernel_launch(void* const* d_in, const int* in_sizes, int n_in,
                              void* d_out, int out_size, void* d_ws, size_t ws_size,
                              hipStream_t stream) {
  const float* x   = (const float*)d_in[0];   // [B*P, D] f32
  const float* pos = (const float*)d_in[1];   // [B*P, 3] f32
  // d_in[2] = batch_idx (int64): sorted equal-sized batches -> layout implied
  int* idx = (int*)d_ws;                      // [B][kN1] int32 = 64 KiB

  fps_kernel<<<kB, kFpsThreads, 0, stream>>>(pos, idx);
  gather_kernel<<<kXBlocks + kPosBlocks, 256, 0, stream>>>(x, pos, idx, (float*)d_out);
}